// Round 7
// baseline (204.821 us; speedup 1.0000x reference)
//
#include <hip/hip_runtime.h>
#include <math.h>

// CrossDomainBridge — MI355X split-bf16 MFMA mega-kernel (round 7).
//
// Math shortcut (exact): softmax rows sum to 1 => corr == 1/2048, dw == 1/8,
// corr_mean == 1/2048; gate bias folds: bg_eff = bg + (1/2048)*sum(Wg[128:131]).
//
// Round-6 lesson: per-kc serial chains (B-frag L2 load ~300cyc -> ~30cyc of
// MFMA) left 60% of cycles idle; traffic was NOT the binding constraint.
// Restructure: (a) waves split the n-dim only and each wave computes BOTH
// m-tiles -> each B-fragment feeds 6 MFMAs (2x reuse, half the global
// loads); (b) whole per-phase B-slice burst-prefetched into VGPRs (one
// latency exposure per phase instead of per kc).
// Weights pre-packed in d_ws (needs >= 655360 B).
//
// d_out layout (floats): out[2097152] corr[72] dw[24] enh0 enh1 enh2

typedef __attribute__((ext_vector_type(8))) short short8;
typedef __attribute__((ext_vector_type(4))) float f32x4;
#define MFMA(a, b, c) __builtin_amdgcn_mfma_f32_16x16x32_bf16(a, b, c, 0, 0, 0)

#define NTOK 32

// ws layout (elems, bf16): each matrix [hi S][lo S]
#define WD0_B 0u
#define WD1_B 32768u
#define WD2_B 65536u
#define WT_B  98304u
#define WG_B  163840u
#define WF0_B 196608u
#define WF1_B 229376u
#define WF2_B 262144u
#define WDF_B 294912u

__device__ __forceinline__ unsigned short bf16rtn(float v) {
    unsigned u = __float_as_uint(v);
    unsigned r = u + 0x7FFFu + ((u >> 16) & 1u);
    return (unsigned short)(r >> 16);
}
__device__ __forceinline__ void split2(float v, unsigned short& h, unsigned short& l) {
    h = bf16rtn(v);
    float hf = __uint_as_float(((unsigned)h) << 16);
    l = bf16rtn(v - hf);
}
__device__ __forceinline__ float bf2f(unsigned short h) {
    return __uint_as_float(((unsigned)h) << 16);
}

// Pack weights into fragment-linear split-bf16: for matrix W[K][N], frag
// (nt,kc): lane holds W[kc*32+(lane>>4)*8 + j][nt*16+(lane&15)], j=0..7.
__global__ __launch_bounds__(256) void prep_kernel(
    const float* __restrict__ Ws, const float* __restrict__ Wf,
    const float* __restrict__ Ww, const float* __restrict__ Wt,
    const float* __restrict__ Wg, const float* __restrict__ Wfu,
    const float* __restrict__ Wdf, unsigned short* __restrict__ ws)
{
    int s = blockIdx.x * 256 + threadIdx.x;   // 0..20479 frag-lane slots
    const float* src; int K, N; unsigned base, S; int fi;
    if (s < 2048)      { src = Ws;            K = 64;  N = 256; base = WD0_B; S = 16384; fi = s; }
    else if (s < 4096) { src = Wf;            K = 64;  N = 256; base = WD1_B; S = 16384; fi = s - 2048; }
    else if (s < 6144) { src = Ww;            K = 64;  N = 256; base = WD2_B; S = 16384; fi = s - 4096; }
    else if (s < 10240){ src = Wt;            K = 256; N = 128; base = WT_B;  S = 32768; fi = s - 6144; }
    else if (s < 12288){ src = Wg;            K = 128; N = 128; base = WG_B;  S = 16384; fi = s - 10240; }
    else if (s < 14336){ src = Wfu;           K = 128; N = 128; base = WF0_B; S = 16384; fi = s - 12288; }
    else if (s < 16384){ src = Wfu + 16384;   K = 128; N = 128; base = WF1_B; S = 16384; fi = s - 14336; }
    else if (s < 18432){ src = Wfu + 32768;   K = 128; N = 128; base = WF2_B; S = 16384; fi = s - 16384; }
    else               { src = Wdf;           K = 128; N = 128; base = WDF_B; S = 16384; fi = s - 18432; }
    const int lane = fi & 63, frag = fi >> 6;
    const int KC = K >> 5;
    const int nt = frag / KC, kc = frag - nt * KC;
    const int n  = nt * 16 + (lane & 15);
    const int k0 = kc * 32 + (lane >> 4) * 8;
    short8 hv, lv;
    #pragma unroll
    for (int j = 0; j < 8; ++j) {
        unsigned short h, l;
        split2(src[(k0 + j) * N + n], h, l);
        hv[j] = (short)h; lv[j] = (short)l;
    }
    *(short8*)&ws[base + (unsigned)fi * 8]     = hv;
    *(short8*)&ws[base + S + (unsigned)fi * 8] = lv;
}

__global__ __launch_bounds__(512, 4) void mega_kernel(
    const float* __restrict__ x0, const float* __restrict__ x1,
    const float* __restrict__ x2,
    const float* __restrict__ bd0, const float* __restrict__ bd1,
    const float* __restrict__ bd2,
    const float* __restrict__ g1, const float* __restrict__ b1,
    const float* __restrict__ bt, const float* __restrict__ Wg,
    const float* __restrict__ bg, const float* __restrict__ bfu,
    const float* __restrict__ bdf, const float* __restrict__ g2,
    const float* __restrict__ b2,
    const unsigned short* __restrict__ ws,
    float* __restrict__ out, float* __restrict__ consts,
    float* __restrict__ e0, float* __restrict__ e1, float* __restrict__ e2)
{
    // 53248 B carve with aliasing -> 3 blocks/CU:
    //   [0,17408):      xh/xl[32*72] (9216B)  UNION  th/tl[32*136] (17408B)
    //   [17408,51200):  ah/al[32*264] (33792B) UNION ostage[32*128]f32 (16KB)
    //   [51200,53248):  psumS[32][8], psumQ[32][8]
    __shared__ __align__(16) unsigned char smem[53248];
    unsigned short* xh = (unsigned short*)smem;            // [32][72]
    unsigned short* xl = xh + 32 * 72;
    unsigned short* th = (unsigned short*)smem;            // [32][136] (t -> enh -> fused)
    unsigned short* tl = th + 32 * 136;
    unsigned short* ah = (unsigned short*)(smem + 17408);  // [32][264]
    unsigned short* al = ah + 32 * 264;
    float* ostage = (float*)(smem + 17408);                // aliases ah/al (dead at epilogue)
    float* psumS  = (float*)(smem + 51200);                // [32][8]
    float* psumQ  = psumS + 32 * 8;                        // [32][8]

    const int tid = threadIdx.x, wv = tid >> 6, lane = tid & 63;
    const int lm = lane & 15, quad = lane >> 4;
    const int row0 = blockIdx.x * NTOK;
    const int tok0 = lm, tok1 = lm + 16;

    if (blockIdx.x == 0) {
        if (tid < 72) consts[tid] = 4.8828125e-4f;      // corr = 1/2048
        else if (tid < 96) consts[tid] = 0.125f;        // dw = 1/8
    }

    // columns: phase A -> 2 ntiles/wave (32 cols); 128-col phases -> 1 ntile
    int cA[2]; float g1c[2], b1c[2];
    #pragma unroll
    for (int i = 0; i < 2; ++i) { cA[i] = (wv * 2 + i) * 16 + lm; g1c[i] = g1[cA[i]]; b1c[i] = b1[cA[i]]; }
    const int cT = wv * 16 + lm;
    const float btc = bt[cT];
    const float bgc = bg[cT] + 4.8828125e-4f * (Wg[16384 + cT] + Wg[16512 + cT] + Wg[16640 + cT]);
    const float bdc = bdf[cT], g2c = g2[cT], b2c = b2[cT];
    f32x4 facc[2];
    { const float bv = bfu[cT]; facc[0] = (f32x4){bv, bv, bv, bv}; facc[1] = facc[0]; }

    const float* xs[3]  = {x0, x1, x2};
    const float* bds[3] = {bd0, bd1, bd2};
    float* es[3] = {e0, e1, e2};
    const unsigned WDB[3] = {WD0_B, WD1_B, WD2_B};
    const unsigned WFB[3] = {WF0_B, WF1_B, WF2_B};

    for (int d = 0; d < 3; ++d) {
        __syncthreads();                    // prev-domain th/tl readers done (x aliases them)
        {   // stage x split: 1 nontemporal float4 per thread
            const int tok = tid >> 4, c4 = (tid & 15) * 4;
            const f32x4 v = __builtin_nontemporal_load(
                (const f32x4*)&xs[d][(row0 + tok) * 64 + c4]);
            unsigned short h0, l0, h1, l1, h2, l2, h3, l3;
            split2(v.x, h0, l0); split2(v.y, h1, l1);
            split2(v.z, h2, l2); split2(v.w, h3, l3);
            *(ushort4*)&xh[tok * 72 + c4] = make_ushort4(h0, h1, h2, h3);
            *(ushort4*)&xl[tok * 72 + c4] = make_ushort4(l0, l1, l2, l3);
        }
        __syncthreads();

        // ---- Phase A: a_raw = x @ Wd + bd. 2 ntiles x 2 mtiles, B burst ----
        f32x4 acc[2][2];                    // [ntile i][mtile m]
        {
            const float* bdp = bds[d];
            #pragma unroll
            for (int i = 0; i < 2; ++i) {
                const float bv = bdp[cA[i]];
                acc[i][0] = (f32x4){bv, bv, bv, bv}; acc[i][1] = acc[i][0];
            }
        }
        {
            short8 Bh[2][2], Bl[2][2];      // [i][kc]
            #pragma unroll
            for (int i = 0; i < 2; ++i)
                #pragma unroll
                for (int kc = 0; kc < 2; ++kc) {
                    const unsigned short* bp = ws + WDB[d] +
                        ((unsigned)((wv * 2 + i) * 2 + kc) * 64 + lane) * 8;
                    Bh[i][kc] = *(const short8*)bp;
                    Bl[i][kc] = *(const short8*)(bp + 16384);
                }
            #pragma unroll
            for (int kc = 0; kc < 2; ++kc) {
                const int k = kc * 32 + quad * 8;
                const short8 Ah0 = *(const short8*)&xh[tok0 * 72 + k];
                const short8 Al0 = *(const short8*)&xl[tok0 * 72 + k];
                const short8 Ah1 = *(const short8*)&xh[tok1 * 72 + k];
                const short8 Al1 = *(const short8*)&xl[tok1 * 72 + k];
                #pragma unroll
                for (int i = 0; i < 2; ++i) {
                    acc[i][0] = MFMA(Ah0, Bh[i][kc], acc[i][0]);
                    acc[i][0] = MFMA(Al0, Bh[i][kc], acc[i][0]);
                    acc[i][0] = MFMA(Ah0, Bl[i][kc], acc[i][0]);
                    acc[i][1] = MFMA(Ah1, Bh[i][kc], acc[i][1]);
                    acc[i][1] = MFMA(Al1, Bh[i][kc], acc[i][1]);
                    acc[i][1] = MFMA(Ah1, Bl[i][kc], acc[i][1]);
                }
            }
        }
        // ---- LN stats: per (m,r) row, partial over this wave's 32 cols ----
        {
            #pragma unroll
            for (int m = 0; m < 2; ++m)
                #pragma unroll
                for (int r = 0; r < 4; ++r) {
                    float s = acc[0][m][r] + acc[1][m][r];
                    float q = acc[0][m][r] * acc[0][m][r] + acc[1][m][r] * acc[1][m][r];
                    #pragma unroll
                    for (int off = 1; off < 16; off <<= 1) {
                        s += __shfl_xor(s, off); q += __shfl_xor(q, off);
                    }
                    if (lm == 0) {
                        const int row = m * 16 + quad * 4 + r;
                        psumS[row * 8 + wv] = s;
                        psumQ[row * 8 + wv] = q;
                    }
                }
        }
        __syncthreads();
        // normalize + split-store a
        #pragma unroll
        for (int m = 0; m < 2; ++m)
            #pragma unroll
            for (int r = 0; r < 4; ++r) {
                const int row = m * 16 + quad * 4 + r;
                const float4 s0 = *(const float4*)&psumS[row * 8];
                const float4 s1 = *(const float4*)&psumS[row * 8 + 4];
                const float4 q0 = *(const float4*)&psumQ[row * 8];
                const float4 q1 = *(const float4*)&psumQ[row * 8 + 4];
                const float S = s0.x + s0.y + s0.z + s0.w + s1.x + s1.y + s1.z + s1.w;
                const float Q = q0.x + q0.y + q0.z + q0.w + q1.x + q1.y + q1.z + q1.w;
                const float mean = S * (1.f / 256.f);
                const float rs = rsqrtf(Q * (1.f / 256.f) - mean * mean + 1e-3f);
                #pragma unroll
                for (int i = 0; i < 2; ++i) {
                    const float v = (acc[i][m][r] - mean) * rs * g1c[i] + b1c[i];
                    unsigned short h, l; split2(v, h, l);
                    ah[row * 264 + cA[i]] = h; al[row * 264 + cA[i]] = l;
                }
            }
        __syncthreads();

        // ---- Phase T: t = a @ Wt + bt. 1 ntile x 2 m, full 8-kc B burst ----
        f32x4 tac[2];
        tac[0] = (f32x4){btc, btc, btc, btc}; tac[1] = tac[0];
        {
            short8 Bh[8], Bl[8];
            #pragma unroll
            for (int kc = 0; kc < 8; ++kc) {
                const unsigned short* bp = ws + WT_B + ((unsigned)(wv * 8 + kc) * 64 + lane) * 8;
                Bh[kc] = *(const short8*)bp;
                Bl[kc] = *(const short8*)(bp + 32768);
            }
            #pragma unroll
            for (int kc = 0; kc < 8; ++kc) {
                const int k = kc * 32 + quad * 8;
                const short8 Ah0 = *(const short8*)&ah[tok0 * 264 + k];
                const short8 Al0 = *(const short8*)&al[tok0 * 264 + k];
                const short8 Ah1 = *(const short8*)&ah[tok1 * 264 + k];
                const short8 Al1 = *(const short8*)&al[tok1 * 264 + k];
                tac[0] = MFMA(Ah0, Bh[kc], tac[0]);
                tac[0] = MFMA(Al0, Bh[kc], tac[0]);
                tac[0] = MFMA(Ah0, Bl[kc], tac[0]);
                tac[1] = MFMA(Ah1, Bh[kc], tac[1]);
                tac[1] = MFMA(Al1, Bh[kc], tac[1]);
                tac[1] = MFMA(Ah1, Bl[kc], tac[1]);
            }
        }
        __syncthreads();                    // xh/xl dead -> th/tl region free
        // t -> split planes (each lane writes its own (row, cT) cells)
        unsigned short tsp[2][4][2];        // [m][r][h/l]
        #pragma unroll
        for (int m = 0; m < 2; ++m)
            #pragma unroll
            for (int r = 0; r < 4; ++r) {
                const int row = m * 16 + quad * 4 + r;
                unsigned short h, l; split2(tac[m][r], h, l);
                tsp[m][r][0] = h; tsp[m][r][1] = l;
                th[row * 136 + cT] = h; tl[row * 136 + cT] = l;
            }
        __syncthreads();

        // ---- Phase G: z = t @ Wg0 + bg_eff. 4-kc B burst ----
        f32x4 zac[2];
        zac[0] = (f32x4){bgc, bgc, bgc, bgc}; zac[1] = zac[0];
        {
            short8 Bh[4], Bl[4];
            #pragma unroll
            for (int kc = 0; kc < 4; ++kc) {
                const unsigned short* bp = ws + WG_B + ((unsigned)(wv * 4 + kc) * 64 + lane) * 8;
                Bh[kc] = *(const short8*)bp;
                Bl[kc] = *(const short8*)(bp + 16384);
            }
            #pragma unroll
            for (int kc = 0; kc < 4; ++kc) {
                const int k = kc * 32 + quad * 8;
                const short8 Ah0 = *(const short8*)&th[tok0 * 136 + k];
                const short8 Al0 = *(const short8*)&tl[tok0 * 136 + k];
                const short8 Ah1 = *(const short8*)&th[tok1 * 136 + k];
                const short8 Al1 = *(const short8*)&tl[tok1 * 136 + k];
                zac[0] = MFMA(Ah0, Bh[kc], zac[0]);
                zac[0] = MFMA(Al0, Bh[kc], zac[0]);
                zac[0] = MFMA(Ah0, Bl[kc], zac[0]);
                zac[1] = MFMA(Ah1, Bh[kc], zac[1]);
                zac[1] = MFMA(Al1, Bh[kc], zac[1]);
                zac[1] = MFMA(Ah1, Bl[kc], zac[1]);
            }
        }
        // enh = t * sigmoid(z) * 0.125 — t reconstructed locally from tsp
        float er[2][4];
        #pragma unroll
        for (int m = 0; m < 2; ++m)
            #pragma unroll
            for (int r = 0; r < 4; ++r) {
                const float tv = bf2f(tsp[m][r][0]) + bf2f(tsp[m][r][1]);
                er[m][r] = tv * (1.f / (1.f + __expf(-zac[m][r]))) * 0.125f;
            }
        __syncthreads();                    // all G reads of th/tl done
        #pragma unroll
        for (int m = 0; m < 2; ++m)
            #pragma unroll
            for (int r = 0; r < 4; ++r) {
                const int row = m * 16 + quad * 4 + r;
                unsigned short h, l; split2(er[m][r], h, l);
                th[row * 136 + cT] = h; tl[row * 136 + cT] = l;
            }
        __syncthreads();

        // enh store: 32 lanes x float4 = 512B/row per instruction (full lines)
        #pragma unroll
        for (int p = 0; p < 2; ++p) {
            const int row = (tid >> 5) + p * 16;
            const int c4 = (tid & 31) * 4;
            const ushort4 h0 = *(const ushort4*)&th[row * 136 + c4];
            const ushort4 l0 = *(const ushort4*)&tl[row * 136 + c4];
            f32x4 o = {bf2f(h0.x) + bf2f(l0.x), bf2f(h0.y) + bf2f(l0.y),
                       bf2f(h0.z) + bf2f(l0.z), bf2f(h0.w) + bf2f(l0.w)};
            __builtin_nontemporal_store(o, (f32x4*)(es[d] + (row0 + row) * 128 + c4));
        }

        // ---- Fuse acc: facc += enh_d @ Wfu_d. 4-kc B burst ----
        {
            short8 Bh[4], Bl[4];
            #pragma unroll
            for (int kc = 0; kc < 4; ++kc) {
                const unsigned short* bp = ws + WFB[d] + ((unsigned)(wv * 4 + kc) * 64 + lane) * 8;
                Bh[kc] = *(const short8*)bp;
                Bl[kc] = *(const short8*)(bp + 16384);
            }
            #pragma unroll
            for (int kc = 0; kc < 4; ++kc) {
                const int k = kc * 32 + quad * 8;
                const short8 Ah0 = *(const short8*)&th[tok0 * 136 + k];
                const short8 Al0 = *(const short8*)&tl[tok0 * 136 + k];
                const short8 Ah1 = *(const short8*)&th[tok1 * 136 + k];
                const short8 Al1 = *(const short8*)&tl[tok1 * 136 + k];
                facc[0] = MFMA(Ah0, Bh[kc], facc[0]);
                facc[0] = MFMA(Al0, Bh[kc], facc[0]);
                facc[0] = MFMA(Ah0, Bl[kc], facc[0]);
                facc[1] = MFMA(Ah1, Bh[kc], facc[1]);
                facc[1] = MFMA(Al1, Bh[kc], facc[1]);
                facc[1] = MFMA(Ah1, Bl[kc], facc[1]);
            }
        }
    }

    __syncthreads();
    // fused -> split planes
    #pragma unroll
    for (int m = 0; m < 2; ++m)
        #pragma unroll
        for (int r = 0; r < 4; ++r) {
            const int row = m * 16 + quad * 4 + r;
            unsigned short h, l; split2(facc[m][r], h, l);
            th[row * 136 + cT] = h; tl[row * 136 + cT] = l;
        }
    __syncthreads();

    // ---- df = fused @ Wdf + bdf. 4-kc B burst ----
    f32x4 dac[2];
    dac[0] = (f32x4){bdc, bdc, bdc, bdc}; dac[1] = dac[0];
    {
        short8 Bh[4], Bl[4];
        #pragma unroll
        for (int kc = 0; kc < 4; ++kc) {
            const unsigned short* bp = ws + WDF_B + ((unsigned)(wv * 4 + kc) * 64 + lane) * 8;
            Bh[kc] = *(const short8*)bp;
            Bl[kc] = *(const short8*)(bp + 16384);
        }
        #pragma unroll
        for (int kc = 0; kc < 4; ++kc) {
            const int k = kc * 32 + quad * 8;
            const short8 Ah0 = *(const short8*)&th[tok0 * 136 + k];
            const short8 Al0 = *(const short8*)&tl[tok0 * 136 + k];
            const short8 Ah1 = *(const short8*)&th[tok1 * 136 + k];
            const short8 Al1 = *(const short8*)&tl[tok1 * 136 + k];
            dac[0] = MFMA(Ah0, Bh[kc], dac[0]);
            dac[0] = MFMA(Al0, Bh[kc], dac[0]);
            dac[0] = MFMA(Ah0, Bl[kc], dac[0]);
            dac[1] = MFMA(Ah1, Bh[kc], dac[1]);
            dac[1] = MFMA(Al1, Bh[kc], dac[1]);
            dac[1] = MFMA(Ah1, Bl[kc], dac[1]);
        }
    }

    // ---- final LN over 128 (wave partial = its 16 cols) ----
    #pragma unroll
    for (int m = 0; m < 2; ++m)
        #pragma unroll
        for (int r = 0; r < 4; ++r) {
            float s = dac[m][r];
            float q = dac[m][r] * dac[m][r];
            #pragma unroll
            for (int off = 1; off < 16; off <<= 1) {
                s += __shfl_xor(s, off); q += __shfl_xor(q, off);
            }
            if (lm == 0) {
                const int row = m * 16 + quad * 4 + r;
                psumS[row * 8 + wv] = s;
                psumQ[row * 8 + wv] = q;
            }
        }
    __syncthreads();
    #pragma unroll
    for (int m = 0; m < 2; ++m)
        #pragma unroll
        for (int r = 0; r < 4; ++r) {
            const int row = m * 16 + quad * 4 + r;
            const float4 s0 = *(const float4*)&psumS[row * 8];
            const float4 s1 = *(const float4*)&psumS[row * 8 + 4];
            const float4 q0 = *(const float4*)&psumQ[row * 8];
            const float4 q1 = *(const float4*)&psumQ[row * 8 + 4];
            const float S = s0.x + s0.y + s0.z + s0.w + s1.x + s1.y + s1.z + s1.w;
            const float Q = q0.x + q0.y + q0.z + q0.w + q1.x + q1.y + q1.z + q1.w;
            const float mean = S * (1.f / 128.f);
            const float rs = rsqrtf(Q * (1.f / 128.f) - mean * mean + 1e-3f);
            ostage[row * 128 + cT] = (dac[m][r] - mean) * rs * g2c + b2c;
        }
    __syncthreads();
    // out store: full lines
    #pragma unroll
    for (int p = 0; p < 2; ++p) {
        const int row = (tid >> 5) + p * 16;
        const int c4 = (tid & 31) * 4;
        const f32x4 o = *(const f32x4*)&ostage[row * 128 + c4];
        __builtin_nontemporal_store(o, (f32x4*)(out + (row0 + row) * 128 + c4));
    }
}

extern "C" void kernel_launch(void* const* d_in, const int* in_sizes, int n_in,
                              void* d_out, int out_size, void* d_ws, size_t ws_size,
                              hipStream_t stream) {
    const float* spatial   = (const float*)d_in[0];
    const float* frequency = (const float*)d_in[1];
    const float* wavelet   = (const float*)d_in[2];
    const float* Ws  = (const float*)d_in[3];
    const float* bs  = (const float*)d_in[4];
    const float* Wf  = (const float*)d_in[5];
    const float* bf  = (const float*)d_in[6];
    const float* Ww  = (const float*)d_in[7];
    const float* bw  = (const float*)d_in[8];
    const float* g1  = (const float*)d_in[9];
    const float* b1  = (const float*)d_in[10];
    // d_in[11..14] = Wk, bk, Wq, bq — provably unused (corr is constant)
    const float* Wt  = (const float*)d_in[15];
    const float* bt  = (const float*)d_in[16];
    const float* Wg  = (const float*)d_in[17];
    const float* bg  = (const float*)d_in[18];
    const float* Wfu = (const float*)d_in[19];
    const float* bfu = (const float*)d_in[20];
    const float* Wdf = (const float*)d_in[21];
    const float* bdf = (const float*)d_in[22];
    const float* g2  = (const float*)d_in[23];
    const float* b2  = (const float*)d_in[24];

    float* out    = (float*)d_out;
    float* consts = out + 2097152;          // corr[72] + dw[24]
    float* enh0   = out + 2097248;
    float* enh1   = out + 4194400;
    float* enh2   = out + 6291552;
    unsigned short* wsp = (unsigned short*)d_ws;   // needs 655360 B

    prep_kernel<<<80, 256, 0, stream>>>(Ws, Wf, Ww, Wt, Wg, Wfu, Wdf, wsp);
    mega_kernel<<<16384 / NTOK, 512, 0, stream>>>(
        spatial, frequency, wavelet, bs, bf, bw, g1, b1,
        bt, Wg, bg, bfu, bdf, g2, b2, wsp,
        out, consts, enh0, enh1, enh2);
}

// Round 9
// 184.293 us; speedup vs baseline: 1.1114x; 1.1114x over previous
//
#include <hip/hip_runtime.h>
#include <math.h>

// CrossDomainBridge — MI355X split-bf16 MFMA mega-kernel (round 9).
//
// Math shortcut (exact): softmax rows sum to 1 => corr == 1/2048, dw == 1/8,
// corr_mean == 1/2048; gate bias folds: bg_eff = bg + (1/2048)*sum(Wg[128:131]).
//
// Round-8 lesson: odd-word pitches made short8/ushort4 LDS accesses on odd
// rows 16B-MISALIGNED (UB -> flaky post-timing corruption). Reverted to even
// pitches 72/264/136 (row stride 16B-aligned; tok-indexed b128 reads are only
// 2-way bank-aliased = free). Round-7 lesson kept: no launch_bounds min-occ
// arg (the ",4" imposed a 64-VGPR cap -> scratch spill -> +100MB HBM).
// n-split m-reuse (each B-frag feeds 6 MFMAs) + depth-2 rolling B prefetch.
// Weights pre-packed in d_ws (needs >= 655360 B).
//
// d_out layout (floats): out[2097152] corr[72] dw[24] enh0 enh1 enh2

typedef __attribute__((ext_vector_type(8))) short short8;
typedef __attribute__((ext_vector_type(4))) float f32x4;
#define MFMA(a, b, c) __builtin_amdgcn_mfma_f32_16x16x32_bf16(a, b, c, 0, 0, 0)

#define NTOK 32
#define XP 72      // x plane pitch (shorts): 144B/row, 16B-aligned
#define AP 264     // a plane pitch: 528B/row, 16B-aligned
#define TP 136     // t plane pitch: 272B/row, 16B-aligned

// ws layout (elems, bf16): each matrix [hi S][lo S]
#define WD0_B 0u
#define WD1_B 32768u
#define WD2_B 65536u
#define WT_B  98304u
#define WG_B  163840u
#define WF0_B 196608u
#define WF1_B 229376u
#define WF2_B 262144u
#define WDF_B 294912u

__device__ __forceinline__ unsigned short bf16rtn(float v) {
    unsigned u = __float_as_uint(v);
    unsigned r = u + 0x7FFFu + ((u >> 16) & 1u);
    return (unsigned short)(r >> 16);
}
__device__ __forceinline__ void split2(float v, unsigned short& h, unsigned short& l) {
    h = bf16rtn(v);
    float hf = __uint_as_float(((unsigned)h) << 16);
    l = bf16rtn(v - hf);
}
__device__ __forceinline__ float bf2f(unsigned short h) {
    return __uint_as_float(((unsigned)h) << 16);
}

// Pack weights into fragment-linear split-bf16: for matrix W[K][N], frag
// (nt,kc): lane holds W[kc*32+(lane>>4)*8 + j][nt*16+(lane&15)], j=0..7.
__global__ __launch_bounds__(256) void prep_kernel(
    const float* __restrict__ Ws, const float* __restrict__ Wf,
    const float* __restrict__ Ww, const float* __restrict__ Wt,
    const float* __restrict__ Wg, const float* __restrict__ Wfu,
    const float* __restrict__ Wdf, unsigned short* __restrict__ ws)
{
    int s = blockIdx.x * 256 + threadIdx.x;   // 0..20479 frag-lane slots
    const float* src; int K, N; unsigned base, S; int fi;
    if (s < 2048)      { src = Ws;            K = 64;  N = 256; base = WD0_B; S = 16384; fi = s; }
    else if (s < 4096) { src = Wf;            K = 64;  N = 256; base = WD1_B; S = 16384; fi = s - 2048; }
    else if (s < 6144) { src = Ww;            K = 64;  N = 256; base = WD2_B; S = 16384; fi = s - 4096; }
    else if (s < 10240){ src = Wt;            K = 256; N = 128; base = WT_B;  S = 32768; fi = s - 6144; }
    else if (s < 12288){ src = Wg;            K = 128; N = 128; base = WG_B;  S = 16384; fi = s - 10240; }
    else if (s < 14336){ src = Wfu;           K = 128; N = 128; base = WF0_B; S = 16384; fi = s - 12288; }
    else if (s < 16384){ src = Wfu + 16384;   K = 128; N = 128; base = WF1_B; S = 16384; fi = s - 14336; }
    else if (s < 18432){ src = Wfu + 32768;   K = 128; N = 128; base = WF2_B; S = 16384; fi = s - 16384; }
    else               { src = Wdf;           K = 128; N = 128; base = WDF_B; S = 16384; fi = s - 18432; }
    const int lane = fi & 63, frag = fi >> 6;
    const int KC = K >> 5;
    const int nt = frag / KC, kc = frag - nt * KC;
    const int n  = nt * 16 + (lane & 15);
    const int k0 = kc * 32 + (lane >> 4) * 8;
    short8 hv, lv;
    #pragma unroll
    for (int j = 0; j < 8; ++j) {
        unsigned short h, l;
        split2(src[(k0 + j) * N + n], h, l);
        hv[j] = (short)h; lv[j] = (short)l;
    }
    *(short8*)&ws[base + (unsigned)fi * 8]     = hv;
    *(short8*)&ws[base + S + (unsigned)fi * 8] = lv;
}

// K=128 phase: acc[2] over both m-tiles, depth-2 rolling B prefetch.
__device__ __forceinline__ void gemm128_d2(
    const unsigned short* __restrict__ wsB, unsigned S,
    const unsigned short* __restrict__ Ph, const unsigned short* __restrict__ Pl,
    int tok0, int tok1, int quad, int wv, int lane, f32x4 acc[2])
{
    short8 Bh[2], Bl[2];
    #pragma unroll
    for (int j = 0; j < 2; ++j) {
        const unsigned short* bp = wsB + ((unsigned)(wv * 4 + j) * 64 + lane) * 8;
        Bh[j] = *(const short8*)bp; Bl[j] = *(const short8*)(bp + S);
    }
    #pragma unroll
    for (int kc = 0; kc < 4; ++kc) {
        const short8 bh = Bh[kc & 1], bl = Bl[kc & 1];
        if (kc + 2 < 4) {
            const unsigned short* bp = wsB + ((unsigned)(wv * 4 + kc + 2) * 64 + lane) * 8;
            Bh[kc & 1] = *(const short8*)bp; Bl[kc & 1] = *(const short8*)(bp + S);
        }
        const int k = kc * 32 + quad * 8;
        const short8 Ah0 = *(const short8*)&Ph[tok0 * TP + k];
        const short8 Al0 = *(const short8*)&Pl[tok0 * TP + k];
        const short8 Ah1 = *(const short8*)&Ph[tok1 * TP + k];
        const short8 Al1 = *(const short8*)&Pl[tok1 * TP + k];
        acc[0] = MFMA(Ah0, bh, acc[0]);
        acc[0] = MFMA(Al0, bh, acc[0]);
        acc[0] = MFMA(Ah0, bl, acc[0]);
        acc[1] = MFMA(Ah1, bh, acc[1]);
        acc[1] = MFMA(Al1, bh, acc[1]);
        acc[1] = MFMA(Ah1, bl, acc[1]);
    }
}

__global__ __launch_bounds__(512) void mega_kernel(
    const float* __restrict__ x0, const float* __restrict__ x1,
    const float* __restrict__ x2,
    const float* __restrict__ bd0, const float* __restrict__ bd1,
    const float* __restrict__ bd2,
    const float* __restrict__ g1, const float* __restrict__ b1,
    const float* __restrict__ bt, const float* __restrict__ Wg,
    const float* __restrict__ bg, const float* __restrict__ bfu,
    const float* __restrict__ bdf, const float* __restrict__ g2,
    const float* __restrict__ b2,
    const unsigned short* __restrict__ ws,
    float* __restrict__ out, float* __restrict__ consts,
    float* __restrict__ e0, float* __restrict__ e1, float* __restrict__ e2)
{
    // 53248 B carve with aliasing -> 3 blocks/CU:
    //   [0,17408):      xh/xl[32*72] (9216B) UNION th/tl[32*136] (17408B)
    //   [17408,51200):  ah/al[32*264] (33792B) UNION ostage[32*128]f32 (16KB)
    //   [51200,53248):  psumS[32][8], psumQ[32][8]
    __shared__ __align__(16) unsigned char smem[53248];
    unsigned short* xh = (unsigned short*)smem;            // [32][XP]
    unsigned short* xl = xh + 32 * XP;
    unsigned short* th = (unsigned short*)smem;            // [32][TP] (t -> enh -> fused)
    unsigned short* tl = th + 32 * TP;
    unsigned short* ah = (unsigned short*)(smem + 17408);  // [32][AP]
    unsigned short* al = ah + 32 * AP;
    float* ostage = (float*)(smem + 17408);                // aliases ah/al (dead at epilogue)
    float* psumS  = (float*)(smem + 51200);                // [32][8]
    float* psumQ  = psumS + 32 * 8;                        // [32][8]

    const int tid = threadIdx.x, wv = tid >> 6, lane = tid & 63;
    const int lm = lane & 15, quad = lane >> 4;
    const int row0 = blockIdx.x * NTOK;
    const int tok0 = lm, tok1 = lm + 16;

    if (blockIdx.x == 0) {
        if (tid < 72) consts[tid] = 4.8828125e-4f;      // corr = 1/2048
        else if (tid < 96) consts[tid] = 0.125f;        // dw = 1/8
    }

    // columns: phase A -> 2 ntiles/wave (32 cols); 128-col phases -> 1 ntile
    int cA[2]; float g1c[2], b1c[2];
    #pragma unroll
    for (int i = 0; i < 2; ++i) { cA[i] = (wv * 2 + i) * 16 + lm; g1c[i] = g1[cA[i]]; b1c[i] = b1[cA[i]]; }
    const int cT = wv * 16 + lm;
    const float btc = bt[cT];
    const float bgc = bg[cT] + 4.8828125e-4f * (Wg[16384 + cT] + Wg[16512 + cT] + Wg[16640 + cT]);
    const float bdc = bdf[cT], g2c = g2[cT], b2c = b2[cT];
    f32x4 facc[2];
    { const float bv = bfu[cT]; facc[0] = (f32x4){bv, bv, bv, bv}; facc[1] = facc[0]; }

    const float* xs[3]  = {x0, x1, x2};
    const float* bds[3] = {bd0, bd1, bd2};
    float* es[3] = {e0, e1, e2};
    const unsigned WDB[3] = {WD0_B, WD1_B, WD2_B};
    const unsigned WFB[3] = {WF0_B, WF1_B, WF2_B};

    for (int d = 0; d < 3; ++d) {
        __syncthreads();                    // prev-domain th/tl readers done (x aliases them)
        {   // stage x split: 1 nontemporal float4 per thread
            const int tok = tid >> 4, c4 = (tid & 15) * 4;
            const f32x4 v = __builtin_nontemporal_load(
                (const f32x4*)&xs[d][(row0 + tok) * 64 + c4]);
            unsigned short h0, l0, h1, l1, h2, l2, h3, l3;
            split2(v.x, h0, l0); split2(v.y, h1, l1);
            split2(v.z, h2, l2); split2(v.w, h3, l3);
            *(ushort4*)&xh[tok * XP + c4] = make_ushort4(h0, h1, h2, h3);
            *(ushort4*)&xl[tok * XP + c4] = make_ushort4(l0, l1, l2, l3);
        }
        __syncthreads();

        // ---- Phase A: a_raw = x @ Wd + bd. 2 ntiles x 2 m, depth-2 B roll ----
        f32x4 acc[2][2];                    // [ntile i][mtile m]
        {
            const float* bdp = bds[d];
            #pragma unroll
            for (int i = 0; i < 2; ++i) {
                const float bv = bdp[cA[i]];
                acc[i][0] = (f32x4){bv, bv, bv, bv}; acc[i][1] = acc[i][0];
            }
        }
        {
            // flatten (kc,i) -> f = kc*2+i, 4 frag-pairs, rolling 2-deep
            short8 Bh[2], Bl[2];
            #pragma unroll
            for (int j = 0; j < 2; ++j) {   // f=0,1 -> kc=0, i=j
                const unsigned short* bp = ws + WDB[d] +
                    ((unsigned)((wv * 2 + j) * 2 + 0) * 64 + lane) * 8;
                Bh[j] = *(const short8*)bp; Bl[j] = *(const short8*)(bp + 16384);
            }
            #pragma unroll
            for (int f = 0; f < 4; ++f) {
                const int kc = f >> 1, i = f & 1;
                const short8 bh = Bh[f & 1], bl = Bl[f & 1];
                if (f + 2 < 4) {
                    const int f2 = f + 2;
                    const unsigned short* bp = ws + WDB[d] +
                        ((unsigned)((wv * 2 + (f2 & 1)) * 2 + (f2 >> 1)) * 64 + lane) * 8;
                    Bh[f & 1] = *(const short8*)bp; Bl[f & 1] = *(const short8*)(bp + 16384);
                }
                const int k = kc * 32 + quad * 8;
                const short8 Ah0 = *(const short8*)&xh[tok0 * XP + k];
                const short8 Al0 = *(const short8*)&xl[tok0 * XP + k];
                const short8 Ah1 = *(const short8*)&xh[tok1 * XP + k];
                const short8 Al1 = *(const short8*)&xl[tok1 * XP + k];
                acc[i][0] = MFMA(Ah0, bh, acc[i][0]);
                acc[i][0] = MFMA(Al0, bh, acc[i][0]);
                acc[i][0] = MFMA(Ah0, bl, acc[i][0]);
                acc[i][1] = MFMA(Ah1, bh, acc[i][1]);
                acc[i][1] = MFMA(Al1, bh, acc[i][1]);
                acc[i][1] = MFMA(Ah1, bl, acc[i][1]);
            }
        }
        // ---- LN stats: per (m,r) row, partial over this wave's 32 cols ----
        {
            #pragma unroll
            for (int m = 0; m < 2; ++m)
                #pragma unroll
                for (int r = 0; r < 4; ++r) {
                    float s = acc[0][m][r] + acc[1][m][r];
                    float q = acc[0][m][r] * acc[0][m][r] + acc[1][m][r] * acc[1][m][r];
                    #pragma unroll
                    for (int off = 1; off < 16; off <<= 1) {
                        s += __shfl_xor(s, off); q += __shfl_xor(q, off);
                    }
                    if (lm == 0) {
                        const int row = m * 16 + quad * 4 + r;
                        psumS[row * 8 + wv] = s;
                        psumQ[row * 8 + wv] = q;
                    }
                }
        }
        __syncthreads();
        // normalize + split-store a
        #pragma unroll
        for (int m = 0; m < 2; ++m)
            #pragma unroll
            for (int r = 0; r < 4; ++r) {
                const int row = m * 16 + quad * 4 + r;
                const float4 s0 = *(const float4*)&psumS[row * 8];
                const float4 s1 = *(const float4*)&psumS[row * 8 + 4];
                const float4 q0 = *(const float4*)&psumQ[row * 8];
                const float4 q1 = *(const float4*)&psumQ[row * 8 + 4];
                const float S = s0.x + s0.y + s0.z + s0.w + s1.x + s1.y + s1.z + s1.w;
                const float Q = q0.x + q0.y + q0.z + q0.w + q1.x + q1.y + q1.z + q1.w;
                const float mean = S * (1.f / 256.f);
                const float rs = rsqrtf(Q * (1.f / 256.f) - mean * mean + 1e-3f);
                #pragma unroll
                for (int i = 0; i < 2; ++i) {
                    const float v = (acc[i][m][r] - mean) * rs * g1c[i] + b1c[i];
                    unsigned short h, l; split2(v, h, l);
                    ah[row * AP + cA[i]] = h; al[row * AP + cA[i]] = l;
                }
            }
        __syncthreads();

        // ---- Phase T: t = a @ Wt + bt. 8 kc, depth-2 B roll ----
        f32x4 tac[2];
        tac[0] = (f32x4){btc, btc, btc, btc}; tac[1] = tac[0];
        {
            short8 Bh[2], Bl[2];
            #pragma unroll
            for (int j = 0; j < 2; ++j) {
                const unsigned short* bp = ws + WT_B + ((unsigned)(wv * 8 + j) * 64 + lane) * 8;
                Bh[j] = *(const short8*)bp; Bl[j] = *(const short8*)(bp + 32768);
            }
            #pragma unroll
            for (int kc = 0; kc < 8; ++kc) {
                const short8 bh = Bh[kc & 1], bl = Bl[kc & 1];
                if (kc + 2 < 8) {
                    const unsigned short* bp = ws + WT_B + ((unsigned)(wv * 8 + kc + 2) * 64 + lane) * 8;
                    Bh[kc & 1] = *(const short8*)bp; Bl[kc & 1] = *(const short8*)(bp + 32768);
                }
                const int k = kc * 32 + quad * 8;
                const short8 Ah0 = *(const short8*)&ah[tok0 * AP + k];
                const short8 Al0 = *(const short8*)&al[tok0 * AP + k];
                const short8 Ah1 = *(const short8*)&ah[tok1 * AP + k];
                const short8 Al1 = *(const short8*)&al[tok1 * AP + k];
                tac[0] = MFMA(Ah0, bh, tac[0]);
                tac[0] = MFMA(Al0, bh, tac[0]);
                tac[0] = MFMA(Ah0, bl, tac[0]);
                tac[1] = MFMA(Ah1, bh, tac[1]);
                tac[1] = MFMA(Al1, bh, tac[1]);
                tac[1] = MFMA(Ah1, bl, tac[1]);
            }
        }
        __syncthreads();                    // xh/xl dead -> th/tl region free
        // t -> split planes; keep lane copies for the gate
        unsigned short tsp[2][4][2];        // [m][r][h/l]
        #pragma unroll
        for (int m = 0; m < 2; ++m)
            #pragma unroll
            for (int r = 0; r < 4; ++r) {
                const int row = m * 16 + quad * 4 + r;
                unsigned short h, l; split2(tac[m][r], h, l);
                tsp[m][r][0] = h; tsp[m][r][1] = l;
                th[row * TP + cT] = h; tl[row * TP + cT] = l;
            }
        __syncthreads();

        // ---- Phase G: z = t @ Wg0 + bg_eff ----
        f32x4 zac[2];
        zac[0] = (f32x4){bgc, bgc, bgc, bgc}; zac[1] = zac[0];
        gemm128_d2(ws + WG_B, 16384, th, tl, tok0, tok1, quad, wv, lane, zac);

        // enh = t * sigmoid(z) * 0.125 — t reconstructed locally from tsp
        float er[2][4];
        #pragma unroll
        for (int m = 0; m < 2; ++m)
            #pragma unroll
            for (int r = 0; r < 4; ++r) {
                const float tv = bf2f(tsp[m][r][0]) + bf2f(tsp[m][r][1]);
                er[m][r] = tv * (1.f / (1.f + __expf(-zac[m][r]))) * 0.125f;
            }
        __syncthreads();                    // all G reads of th/tl done
        #pragma unroll
        for (int m = 0; m < 2; ++m)
            #pragma unroll
            for (int r = 0; r < 4; ++r) {
                const int row = m * 16 + quad * 4 + r;
                unsigned short h, l; split2(er[m][r], h, l);
                th[row * TP + cT] = h; tl[row * TP + cT] = l;
            }
        __syncthreads();

        // enh store: 32 lanes x float4 = 512B/row per instruction (full lines)
        #pragma unroll
        for (int p = 0; p < 2; ++p) {
            const int row = (tid >> 5) + p * 16;
            const int c4 = (tid & 31) * 4;
            const ushort4 h0 = *(const ushort4*)&th[row * TP + c4];
            const ushort4 l0 = *(const ushort4*)&tl[row * TP + c4];
            f32x4 o = {bf2f(h0.x) + bf2f(l0.x), bf2f(h0.y) + bf2f(l0.y),
                       bf2f(h0.z) + bf2f(l0.z), bf2f(h0.w) + bf2f(l0.w)};
            __builtin_nontemporal_store(o, (f32x4*)(es[d] + (row0 + row) * 128 + c4));
        }

        // ---- Fuse acc: facc += enh_d @ Wfu_d ----
        gemm128_d2(ws + WFB[d], 16384, th, tl, tok0, tok1, quad, wv, lane, facc);
    }

    __syncthreads();
    // fused -> split planes
    #pragma unroll
    for (int m = 0; m < 2; ++m)
        #pragma unroll
        for (int r = 0; r < 4; ++r) {
            const int row = m * 16 + quad * 4 + r;
            unsigned short h, l; split2(facc[m][r], h, l);
            th[row * TP + cT] = h; tl[row * TP + cT] = l;
        }
    __syncthreads();

    // ---- df = fused @ Wdf + bdf ----
    f32x4 dac[2];
    dac[0] = (f32x4){bdc, bdc, bdc, bdc}; dac[1] = dac[0];
    gemm128_d2(ws + WDF_B, 16384, th, tl, tok0, tok1, quad, wv, lane, dac);

    // ---- final LN over 128 (wave partial = its 16 cols) ----
    #pragma unroll
    for (int m = 0; m < 2; ++m)
        #pragma unroll
        for (int r = 0; r < 4; ++r) {
            float s = dac[m][r];
            float q = dac[m][r] * dac[m][r];
            #pragma unroll
            for (int off = 1; off < 16; off <<= 1) {
                s += __shfl_xor(s, off); q += __shfl_xor(q, off);
            }
            if (lm == 0) {
                const int row = m * 16 + quad * 4 + r;
                psumS[row * 8 + wv] = s;
                psumQ[row * 8 + wv] = q;
            }
        }
    __syncthreads();
    #pragma unroll
    for (int m = 0; m < 2; ++m)
        #pragma unroll
        for (int r = 0; r < 4; ++r) {
            const int row = m * 16 + quad * 4 + r;
            const float4 s0 = *(const float4*)&psumS[row * 8];
            const float4 s1 = *(const float4*)&psumS[row * 8 + 4];
            const float4 q0 = *(const float4*)&psumQ[row * 8];
            const float4 q1 = *(const float4*)&psumQ[row * 8 + 4];
            const float S = s0.x + s0.y + s0.z + s0.w + s1.x + s1.y + s1.z + s1.w;
            const float Q = q0.x + q0.y + q0.z + q0.w + q1.x + q1.y + q1.z + q1.w;
            const float mean = S * (1.f / 128.f);
            const float rs = rsqrtf(Q * (1.f / 128.f) - mean * mean + 1e-3f);
            ostage[row * 128 + cT] = (dac[m][r] - mean) * rs * g2c + b2c;
        }
    __syncthreads();
    // out store: full lines
    #pragma unroll
    for (int p = 0; p < 2; ++p) {
        const int row = (tid >> 5) + p * 16;
        const int c4 = (tid & 31) * 4;
        const f32x4 o = *(const f32x4*)&ostage[row * 128 + c4];
        __builtin_nontemporal_store(o, (f32x4*)(out + (row0 + row) * 128 + c4));
    }
}

extern "C" void kernel_launch(void* const* d_in, const int* in_sizes, int n_in,
                              void* d_out, int out_size, void* d_ws, size_t ws_size,
                              hipStream_t stream) {
    const float* spatial   = (const float*)d_in[0];
    const float* frequency = (const float*)d_in[1];
    const float* wavelet   = (const float*)d_in[2];
    const float* Ws  = (const float*)d_in[3];
    const float* bs  = (const float*)d_in[4];
    const float* Wf  = (const float*)d_in[5];
    const float* bf  = (const float*)d_in[6];
    const float* Ww  = (const float*)d_in[7];
    const float* bw  = (const float*)d_in[8];
    const float* g1  = (const float*)d_in[9];
    const float* b1  = (const float*)d_in[10];
    // d_in[11..14] = Wk, bk, Wq, bq — provably unused (corr is constant)
    const float* Wt  = (const float*)d_in[15];
    const float* bt  = (const float*)d_in[16];
    const float* Wg  = (const float*)d_in[17];
    const float* bg  = (const float*)d_in[18];
    const float* Wfu = (const float*)d_in[19];
    const float* bfu = (const float*)d_in[20];
    const float* Wdf = (const float*)d_in[21];
    const float* bdf = (const float*)d_in[22];
    const float* g2  = (const float*)d_in[23];
    const float* b2  = (const float*)d_in[24];

    float* out    = (float*)d_out;
    float* consts = out + 2097152;          // corr[72] + dw[24]
    float* enh0   = out + 2097248;
    float* enh1   = out + 4194400;
    float* enh2   = out + 6291552;
    unsigned short* wsp = (unsigned short*)d_ws;   // needs 655360 B

    prep_kernel<<<80, 256, 0, stream>>>(Ws, Wf, Ww, Wt, Wg, Wfu, Wdf, wsp);
    mega_kernel<<<16384 / NTOK, 512, 0, stream>>>(
        spatial, frequency, wavelet, bs, bf, bw, g1, b1,
        bt, Wg, bg, bfu, bdf, g2, b2, wsp,
        out, consts, enh0, enh1, enh2);
}

// Round 10
// 181.339 us; speedup vs baseline: 1.1295x; 1.0163x over previous
//
#include <hip/hip_runtime.h>
#include <math.h>

// CrossDomainBridge — MI355X split-bf16 MFMA mega-kernel (round 10).
//
// Math shortcut (exact): softmax rows sum to 1 => corr == 1/2048, dw == 1/8,
// corr_mean == 1/2048; gate bias folds: bg_eff = bg + (1/2048)*sum(Wg[128:131]).
//
// Round-9 lesson: traffic is clean (FETCH 9MB / WRITE 33MB) but ~60% of
// cycles idle — the 28-barrier phase chain serializes (2 phase-locked
// blocks/CU). This round: barrier schedule re-derived from the hazard graph
// -> 18 barriers: (a) enh planes go to the ah/al region (free after phase T)
// so the th/tl overwrite round-trip loses 2 barriers; (b) next domain's x
// tile is register-prefetched during phase T and split-stored during the
// fuse phase (th/tl free after phase G) — loop-top barrier and exposed HBM
// latency gone. Layouts/pitches/depth-2 B roll unchanged from round 9.
// Weights pre-packed in d_ws (needs >= 655360 B).
//
// d_out layout (floats): out[2097152] corr[72] dw[24] enh0 enh1 enh2

typedef __attribute__((ext_vector_type(8))) short short8;
typedef __attribute__((ext_vector_type(4))) float f32x4;
#define MFMA(a, b, c) __builtin_amdgcn_mfma_f32_16x16x32_bf16(a, b, c, 0, 0, 0)

#define NTOK 32
#define XP 72      // x plane pitch (shorts): 16B-aligned rows
#define AP 264     // a plane pitch
#define TP 136     // t/enh/fused plane pitch

// ws layout (elems, bf16): each matrix [hi S][lo S]
#define WD0_B 0u
#define WD1_B 32768u
#define WD2_B 65536u
#define WT_B  98304u
#define WG_B  163840u
#define WF0_B 196608u
#define WF1_B 229376u
#define WF2_B 262144u
#define WDF_B 294912u

__device__ __forceinline__ unsigned short bf16rtn(float v) {
    unsigned u = __float_as_uint(v);
    unsigned r = u + 0x7FFFu + ((u >> 16) & 1u);
    return (unsigned short)(r >> 16);
}
__device__ __forceinline__ void split2(float v, unsigned short& h, unsigned short& l) {
    h = bf16rtn(v);
    float hf = __uint_as_float(((unsigned)h) << 16);
    l = bf16rtn(v - hf);
}
__device__ __forceinline__ float bf2f(unsigned short h) {
    return __uint_as_float(((unsigned)h) << 16);
}

// Pack weights into fragment-linear split-bf16: for matrix W[K][N], frag
// (nt,kc): lane holds W[kc*32+(lane>>4)*8 + j][nt*16+(lane&15)], j=0..7.
__global__ __launch_bounds__(256) void prep_kernel(
    const float* __restrict__ Ws, const float* __restrict__ Wf,
    const float* __restrict__ Ww, const float* __restrict__ Wt,
    const float* __restrict__ Wg, const float* __restrict__ Wfu,
    const float* __restrict__ Wdf, unsigned short* __restrict__ ws)
{
    int s = blockIdx.x * 256 + threadIdx.x;   // 0..20479 frag-lane slots
    const float* src; int K, N; unsigned base, S; int fi;
    if (s < 2048)      { src = Ws;            K = 64;  N = 256; base = WD0_B; S = 16384; fi = s; }
    else if (s < 4096) { src = Wf;            K = 64;  N = 256; base = WD1_B; S = 16384; fi = s - 2048; }
    else if (s < 6144) { src = Ww;            K = 64;  N = 256; base = WD2_B; S = 16384; fi = s - 4096; }
    else if (s < 10240){ src = Wt;            K = 256; N = 128; base = WT_B;  S = 32768; fi = s - 6144; }
    else if (s < 12288){ src = Wg;            K = 128; N = 128; base = WG_B;  S = 16384; fi = s - 10240; }
    else if (s < 14336){ src = Wfu;           K = 128; N = 128; base = WF0_B; S = 16384; fi = s - 12288; }
    else if (s < 16384){ src = Wfu + 16384;   K = 128; N = 128; base = WF1_B; S = 16384; fi = s - 14336; }
    else if (s < 18432){ src = Wfu + 32768;   K = 128; N = 128; base = WF2_B; S = 16384; fi = s - 16384; }
    else               { src = Wdf;           K = 128; N = 128; base = WDF_B; S = 16384; fi = s - 18432; }
    const int lane = fi & 63, frag = fi >> 6;
    const int KC = K >> 5;
    const int nt = frag / KC, kc = frag - nt * KC;
    const int n  = nt * 16 + (lane & 15);
    const int k0 = kc * 32 + (lane >> 4) * 8;
    short8 hv, lv;
    #pragma unroll
    for (int j = 0; j < 8; ++j) {
        unsigned short h, l;
        split2(src[(k0 + j) * N + n], h, l);
        hv[j] = (short)h; lv[j] = (short)l;
    }
    *(short8*)&ws[base + (unsigned)fi * 8]     = hv;
    *(short8*)&ws[base + S + (unsigned)fi * 8] = lv;
}

// K=128 phase: acc[2] over both m-tiles, depth-2 rolling B prefetch.
// A planes at TP pitch.
__device__ __forceinline__ void gemm128_d2(
    const unsigned short* __restrict__ wsB, unsigned S,
    const unsigned short* __restrict__ Ph, const unsigned short* __restrict__ Pl,
    int tok0, int tok1, int quad, int wv, int lane, f32x4 acc[2])
{
    short8 Bh[2], Bl[2];
    #pragma unroll
    for (int j = 0; j < 2; ++j) {
        const unsigned short* bp = wsB + ((unsigned)(wv * 4 + j) * 64 + lane) * 8;
        Bh[j] = *(const short8*)bp; Bl[j] = *(const short8*)(bp + S);
    }
    #pragma unroll
    for (int kc = 0; kc < 4; ++kc) {
        const short8 bh = Bh[kc & 1], bl = Bl[kc & 1];
        if (kc + 2 < 4) {
            const unsigned short* bp = wsB + ((unsigned)(wv * 4 + kc + 2) * 64 + lane) * 8;
            Bh[kc & 1] = *(const short8*)bp; Bl[kc & 1] = *(const short8*)(bp + S);
        }
        const int k = kc * 32 + quad * 8;
        const short8 Ah0 = *(const short8*)&Ph[tok0 * TP + k];
        const short8 Al0 = *(const short8*)&Pl[tok0 * TP + k];
        const short8 Ah1 = *(const short8*)&Ph[tok1 * TP + k];
        const short8 Al1 = *(const short8*)&Pl[tok1 * TP + k];
        acc[0] = MFMA(Ah0, bh, acc[0]);
        acc[0] = MFMA(Al0, bh, acc[0]);
        acc[0] = MFMA(Ah0, bl, acc[0]);
        acc[1] = MFMA(Ah1, bh, acc[1]);
        acc[1] = MFMA(Al1, bh, acc[1]);
        acc[1] = MFMA(Ah1, bl, acc[1]);
    }
}

__global__ __launch_bounds__(512) void mega_kernel(
    const float* __restrict__ x0, const float* __restrict__ x1,
    const float* __restrict__ x2,
    const float* __restrict__ bd0, const float* __restrict__ bd1,
    const float* __restrict__ bd2,
    const float* __restrict__ g1, const float* __restrict__ b1,
    const float* __restrict__ bt, const float* __restrict__ Wg,
    const float* __restrict__ bg, const float* __restrict__ bfu,
    const float* __restrict__ bdf, const float* __restrict__ g2,
    const float* __restrict__ b2,
    const unsigned short* __restrict__ ws,
    float* __restrict__ out, float* __restrict__ consts,
    float* __restrict__ e0, float* __restrict__ e1, float* __restrict__ e2)
{
    // 53248 B carve with aliasing (2+ blocks/CU):
    //   [0,17408):      xh/xl[32*72] UNION th/tl[32*136] (x -> t -> fused)
    //   [17408,51200):  ah/al[32*264] UNION eh/el[32*136] (a -> enh) UNION ostage
    //   [51200,53248):  psumS[32][8], psumQ[32][8]
    __shared__ __align__(16) unsigned char smem[53248];
    unsigned short* xh = (unsigned short*)smem;            // [32][XP]
    unsigned short* xl = xh + 32 * XP;
    unsigned short* th = (unsigned short*)smem;            // [32][TP]
    unsigned short* tl = th + 32 * TP;
    unsigned short* ah = (unsigned short*)(smem + 17408);  // [32][AP]
    unsigned short* al = ah + 32 * AP;
    unsigned short* eh = (unsigned short*)(smem + 17408);  // [32][TP] enh planes
    unsigned short* el = eh + 32 * TP;
    float* ostage = (float*)(smem + 17408);                // aliases ah/eh (dead at epilogue)
    float* psumS  = (float*)(smem + 51200);                // [32][8]
    float* psumQ  = psumS + 32 * 8;                        // [32][8]

    const int tid = threadIdx.x, wv = tid >> 6, lane = tid & 63;
    const int lm = lane & 15, quad = lane >> 4;
    const int row0 = blockIdx.x * NTOK;
    const int tok0 = lm, tok1 = lm + 16;
    const int stok = tid >> 4, sc4 = (tid & 15) * 4;   // x-staging coords

    if (blockIdx.x == 0) {
        if (tid < 72) consts[tid] = 4.8828125e-4f;      // corr = 1/2048
        else if (tid < 96) consts[tid] = 0.125f;        // dw = 1/8
    }

    // columns: phase A -> 2 ntiles/wave (32 cols); 128-col phases -> 1 ntile
    int cA[2]; float g1c[2], b1c[2];
    #pragma unroll
    for (int i = 0; i < 2; ++i) { cA[i] = (wv * 2 + i) * 16 + lm; g1c[i] = g1[cA[i]]; b1c[i] = b1[cA[i]]; }
    const int cT = wv * 16 + lm;
    const float btc = bt[cT];
    const float bgc = bg[cT] + 4.8828125e-4f * (Wg[16384 + cT] + Wg[16512 + cT] + Wg[16640 + cT]);
    const float bdc = bdf[cT], g2c = g2[cT], b2c = b2[cT];
    f32x4 facc[2];
    { const float bv = bfu[cT]; facc[0] = (f32x4){bv, bv, bv, bv}; facc[1] = facc[0]; }

    const float* xs[3]  = {x0, x1, x2};
    const float* bds[3] = {bd0, bd1, bd2};
    float* es[3] = {e0, e1, e2};
    const unsigned WDB[3] = {WD0_B, WD1_B, WD2_B};
    const unsigned WFB[3] = {WF0_B, WF1_B, WF2_B};

    // ---- pre-loop: stage x for d=0 ----
    {
        const f32x4 v = __builtin_nontemporal_load(
            (const f32x4*)&xs[0][(row0 + stok) * 64 + sc4]);
        unsigned short h0, l0, h1, l1, h2, l2, h3, l3;
        split2(v.x, h0, l0); split2(v.y, h1, l1);
        split2(v.z, h2, l2); split2(v.w, h3, l3);
        *(ushort4*)&xh[stok * XP + sc4] = make_ushort4(h0, h1, h2, h3);
        *(ushort4*)&xl[stok * XP + sc4] = make_ushort4(l0, l1, l2, l3);
    }
    __syncthreads();                        // B_a: x(0) planes ready

    for (int d = 0; d < 3; ++d) {
        // ---- Phase A: a_raw = x @ Wd + bd. 2 ntiles x 2 m, depth-2 B roll ----
        f32x4 acc[2][2];                    // [ntile i][mtile m]
        {
            const float* bdp = bds[d];
            #pragma unroll
            for (int i = 0; i < 2; ++i) {
                const float bv = bdp[cA[i]];
                acc[i][0] = (f32x4){bv, bv, bv, bv}; acc[i][1] = acc[i][0];
            }
        }
        {
            short8 Bh[2], Bl[2];
            #pragma unroll
            for (int j = 0; j < 2; ++j) {   // f=0,1 -> kc=0, i=j
                const unsigned short* bp = ws + WDB[d] +
                    ((unsigned)((wv * 2 + j) * 2 + 0) * 64 + lane) * 8;
                Bh[j] = *(const short8*)bp; Bl[j] = *(const short8*)(bp + 16384);
            }
            #pragma unroll
            for (int f = 0; f < 4; ++f) {   // f = kc*2 + i
                const int kc = f >> 1, i = f & 1;
                const short8 bh = Bh[f & 1], bl = Bl[f & 1];
                if (f + 2 < 4) {
                    const int f2 = f + 2;
                    const unsigned short* bp = ws + WDB[d] +
                        ((unsigned)((wv * 2 + (f2 & 1)) * 2 + (f2 >> 1)) * 64 + lane) * 8;
                    Bh[f & 1] = *(const short8*)bp; Bl[f & 1] = *(const short8*)(bp + 16384);
                }
                const int k = kc * 32 + quad * 8;
                const short8 Ah0 = *(const short8*)&xh[tok0 * XP + k];
                const short8 Al0 = *(const short8*)&xl[tok0 * XP + k];
                const short8 Ah1 = *(const short8*)&xh[tok1 * XP + k];
                const short8 Al1 = *(const short8*)&xl[tok1 * XP + k];
                acc[i][0] = MFMA(Ah0, bh, acc[i][0]);
                acc[i][0] = MFMA(Al0, bh, acc[i][0]);
                acc[i][0] = MFMA(Ah0, bl, acc[i][0]);
                acc[i][1] = MFMA(Ah1, bh, acc[i][1]);
                acc[i][1] = MFMA(Al1, bh, acc[i][1]);
                acc[i][1] = MFMA(Ah1, bl, acc[i][1]);
            }
        }
        // LN partials over this wave's 32 cols
        #pragma unroll
        for (int m = 0; m < 2; ++m)
            #pragma unroll
            for (int r = 0; r < 4; ++r) {
                float s = acc[0][m][r] + acc[1][m][r];
                float q = acc[0][m][r] * acc[0][m][r] + acc[1][m][r] * acc[1][m][r];
                #pragma unroll
                for (int off = 1; off < 16; off <<= 1) {
                    s += __shfl_xor(s, off); q += __shfl_xor(q, off);
                }
                if (lm == 0) {
                    const int row = m * 16 + quad * 4 + r;
                    psumS[row * 8 + wv] = s;
                    psumQ[row * 8 + wv] = q;
                }
            }
        __syncthreads();                    // B_b: psum ready (also: all x reads done)

        // normalize + a-planes store (ah/al)
        #pragma unroll
        for (int m = 0; m < 2; ++m)
            #pragma unroll
            for (int r = 0; r < 4; ++r) {
                const int row = m * 16 + quad * 4 + r;
                const float4 s0 = *(const float4*)&psumS[row * 8];
                const float4 s1 = *(const float4*)&psumS[row * 8 + 4];
                const float4 q0 = *(const float4*)&psumQ[row * 8];
                const float4 q1 = *(const float4*)&psumQ[row * 8 + 4];
                const float S = s0.x + s0.y + s0.z + s0.w + s1.x + s1.y + s1.z + s1.w;
                const float Q = q0.x + q0.y + q0.z + q0.w + q1.x + q1.y + q1.z + q1.w;
                const float mean = S * (1.f / 256.f);
                const float rs = rsqrtf(Q * (1.f / 256.f) - mean * mean + 1e-3f);
                #pragma unroll
                for (int i = 0; i < 2; ++i) {
                    const float v = (acc[i][m][r] - mean) * rs * g1c[i] + b1c[i];
                    unsigned short h, l; split2(v, h, l);
                    ah[row * AP + cA[i]] = h; al[row * AP + cA[i]] = l;
                }
            }
        __syncthreads();                    // B_c: a planes ready

        // prefetch next domain's x into regs (used after B_e — latency hidden)
        f32x4 xvn;
        if (d < 2)
            xvn = __builtin_nontemporal_load(
                (const f32x4*)&xs[d + 1][(row0 + stok) * 64 + sc4]);

        // ---- Phase T: t = a @ Wt + bt. 8 kc, depth-2 B roll ----
        f32x4 tac[2];
        tac[0] = (f32x4){btc, btc, btc, btc}; tac[1] = tac[0];
        {
            short8 Bh[2], Bl[2];
            #pragma unroll
            for (int j = 0; j < 2; ++j) {
                const unsigned short* bp = ws + WT_B + ((unsigned)(wv * 8 + j) * 64 + lane) * 8;
                Bh[j] = *(const short8*)bp; Bl[j] = *(const short8*)(bp + 32768);
            }
            #pragma unroll
            for (int kc = 0; kc < 8; ++kc) {
                const short8 bh = Bh[kc & 1], bl = Bl[kc & 1];
                if (kc + 2 < 8) {
                    const unsigned short* bp = ws + WT_B + ((unsigned)(wv * 8 + kc + 2) * 64 + lane) * 8;
                    Bh[kc & 1] = *(const short8*)bp; Bl[kc & 1] = *(const short8*)(bp + 32768);
                }
                const int k = kc * 32 + quad * 8;
                const short8 Ah0 = *(const short8*)&ah[tok0 * AP + k];
                const short8 Al0 = *(const short8*)&al[tok0 * AP + k];
                const short8 Ah1 = *(const short8*)&ah[tok1 * AP + k];
                const short8 Al1 = *(const short8*)&al[tok1 * AP + k];
                tac[0] = MFMA(Ah0, bh, tac[0]);
                tac[0] = MFMA(Al0, bh, tac[0]);
                tac[0] = MFMA(Ah0, bl, tac[0]);
                tac[1] = MFMA(Ah1, bh, tac[1]);
                tac[1] = MFMA(Al1, bh, tac[1]);
                tac[1] = MFMA(Ah1, bl, tac[1]);
            }
        }
        // t -> th/tl (x region: all x reads done at B_b; safe to overwrite)
        #pragma unroll
        for (int m = 0; m < 2; ++m)
            #pragma unroll
            for (int r = 0; r < 4; ++r) {
                const int row = m * 16 + quad * 4 + r;
                unsigned short h, l; split2(tac[m][r], h, l);
                th[row * TP + cT] = h; tl[row * TP + cT] = l;
            }
        __syncthreads();                    // B_d: t planes ready (also: all a reads done)

        // ---- Phase G: z = t @ Wg0 + bg_eff ----
        f32x4 zac[2];
        zac[0] = (f32x4){bgc, bgc, bgc, bgc}; zac[1] = zac[0];
        gemm128_d2(ws + WG_B, 16384, th, tl, tok0, tok1, quad, wv, lane, zac);

        // enh = t * sigmoid(z)/8 -> eh/el (a region: free after B_d)
        #pragma unroll
        for (int m = 0; m < 2; ++m)
            #pragma unroll
            for (int r = 0; r < 4; ++r) {
                const int row = m * 16 + quad * 4 + r;
                const float tv = bf2f(th[row * TP + cT]) + bf2f(tl[row * TP + cT]);
                const float e = tv * (1.f / (1.f + __expf(-zac[m][r]))) * 0.125f;
                unsigned short h, l; split2(e, h, l);
                eh[row * TP + cT] = h; el[row * TP + cT] = l;
            }
        __syncthreads();                    // B_e: enh planes ready (also: all t/G reads done)

        // ---- Fuse acc: facc += enh_d @ Wfu_d (reads eh/el) ----
        gemm128_d2(ws + WFB[d], 16384, eh, el, tok0, tok1, quad, wv, lane, facc);

        // enh global store: full 512B rows, nontemporal
        #pragma unroll
        for (int p = 0; p < 2; ++p) {
            const int row = (tid >> 5) + p * 16;
            const int c4 = (tid & 31) * 4;
            const ushort4 h0 = *(const ushort4*)&eh[row * TP + c4];
            const ushort4 l0 = *(const ushort4*)&el[row * TP + c4];
            f32x4 o = {bf2f(h0.x) + bf2f(l0.x), bf2f(h0.y) + bf2f(l0.y),
                       bf2f(h0.z) + bf2f(l0.z), bf2f(h0.w) + bf2f(l0.w)};
            __builtin_nontemporal_store(o, (f32x4*)(es[d] + (row0 + row) * 128 + c4));
        }

        // tail store into th/tl (free after B_e): x(d+1) or fused planes
        if (d < 2) {
            unsigned short h0, l0, h1, l1, h2, l2, h3, l3;
            split2(xvn.x, h0, l0); split2(xvn.y, h1, l1);
            split2(xvn.z, h2, l2); split2(xvn.w, h3, l3);
            *(ushort4*)&xh[stok * XP + sc4] = make_ushort4(h0, h1, h2, h3);
            *(ushort4*)&xl[stok * XP + sc4] = make_ushort4(l0, l1, l2, l3);
        } else {
            #pragma unroll
            for (int m = 0; m < 2; ++m)
                #pragma unroll
                for (int r = 0; r < 4; ++r) {
                    const int row = m * 16 + quad * 4 + r;
                    unsigned short h, l; split2(facc[m][r], h, l);
                    th[row * TP + cT] = h; tl[row * TP + cT] = l;
                }
        }
        __syncthreads();                    // B_f: th/tl ready for next phase
    }

    // ---- df = fused @ Wdf + bdf (reads th/tl) ----
    f32x4 dac[2];
    dac[0] = (f32x4){bdc, bdc, bdc, bdc}; dac[1] = dac[0];
    gemm128_d2(ws + WDF_B, 16384, th, tl, tok0, tok1, quad, wv, lane, dac);

    // ---- final LN over 128 (wave partial = its 16 cols) ----
    #pragma unroll
    for (int m = 0; m < 2; ++m)
        #pragma unroll
        for (int r = 0; r < 4; ++r) {
            float s = dac[m][r];
            float q = dac[m][r] * dac[m][r];
            #pragma unroll
            for (int off = 1; off < 16; off <<= 1) {
                s += __shfl_xor(s, off); q += __shfl_xor(q, off);
            }
            if (lm == 0) {
                const int row = m * 16 + quad * 4 + r;
                psumS[row * 8 + wv] = s;
                psumQ[row * 8 + wv] = q;
            }
        }
    __syncthreads();
    #pragma unroll
    for (int m = 0; m < 2; ++m)
        #pragma unroll
        for (int r = 0; r < 4; ++r) {
            const int row = m * 16 + quad * 4 + r;
            const float4 s0 = *(const float4*)&psumS[row * 8];
            const float4 s1 = *(const float4*)&psumS[row * 8 + 4];
            const float4 q0 = *(const float4*)&psumQ[row * 8];
            const float4 q1 = *(const float4*)&psumQ[row * 8 + 4];
            const float S = s0.x + s0.y + s0.z + s0.w + s1.x + s1.y + s1.z + s1.w;
            const float Q = q0.x + q0.y + q0.z + q0.w + q1.x + q1.y + q1.z + q1.w;
            const float mean = S * (1.f / 128.f);
            const float rs = rsqrtf(Q * (1.f / 128.f) - mean * mean + 1e-3f);
            ostage[row * 128 + cT] = (dac[m][r] - mean) * rs * g2c + b2c;
        }
    __syncthreads();
    // out store: full lines
    #pragma unroll
    for (int p = 0; p < 2; ++p) {
        const int row = (tid >> 5) + p * 16;
        const int c4 = (tid & 31) * 4;
        const f32x4 o = *(const f32x4*)&ostage[row * 128 + c4];
        __builtin_nontemporal_store(o, (f32x4*)(out + (row0 + row) * 128 + c4));
    }
}

extern "C" void kernel_launch(void* const* d_in, const int* in_sizes, int n_in,
                              void* d_out, int out_size, void* d_ws, size_t ws_size,
                              hipStream_t stream) {
    const float* spatial   = (const float*)d_in[0];
    const float* frequency = (const float*)d_in[1];
    const float* wavelet   = (const float*)d_in[2];
    const float* Ws  = (const float*)d_in[3];
    const float* bs  = (const float*)d_in[4];
    const float* Wf  = (const float*)d_in[5];
    const float* bf  = (const float*)d_in[6];
    const float* Ww  = (const float*)d_in[7];
    const float* bw  = (const float*)d_in[8];
    const float* g1  = (const float*)d_in[9];
    const float* b1  = (const float*)d_in[10];
    // d_in[11..14] = Wk, bk, Wq, bq — provably unused (corr is constant)
    const float* Wt  = (const float*)d_in[15];
    const float* bt  = (const float*)d_in[16];
    const float* Wg  = (const float*)d_in[17];
    const float* bg  = (const float*)d_in[18];
    const float* Wfu = (const float*)d_in[19];
    const float* bfu = (const float*)d_in[20];
    const float* Wdf = (const float*)d_in[21];
    const float* bdf = (const float*)d_in[22];
    const float* g2  = (const float*)d_in[23];
    const float* b2  = (const float*)d_in[24];

    float* out    = (float*)d_out;
    float* consts = out + 2097152;          // corr[72] + dw[24]
    float* enh0   = out + 2097248;
    float* enh1   = out + 4194400;
    float* enh2   = out + 6291552;
    unsigned short* wsp = (unsigned short*)d_ws;   // needs 655360 B

    prep_kernel<<<80, 256, 0, stream>>>(Ws, Wf, Ww, Wt, Wg, Wfu, Wdf, wsp);
    mega_kernel<<<16384 / NTOK, 512, 0, stream>>>(
        spatial, frequency, wavelet, bs, bf, bw, g1, b1,
        bt, Wg, bg, bfu, bdf, g2, b2, wsp,
        out, consts, enh0, enh1, enh2);
}